// Round 17
// baseline (302.835 us; speedup 1.0000x reference)
//
#include <hip/hip_runtime.h>
#include <hip/hip_fp16.h>

typedef unsigned short ushort_t;
typedef __attribute__((ext_vector_type(8))) _Float16 half8v;
typedef __attribute__((ext_vector_type(4))) float float4v;
typedef __attribute__((ext_vector_type(8))) unsigned short ushort8v;

#define DEV_INLINE __device__ __forceinline__

DEV_INLINE ushort_t f2h_bits(float f) {
  return __half_as_ushort(__float2half(f));
}

// ---------------- fused: router (blocks 0..2047) + transpose+cvt (r12 body) ----
__global__ __launch_bounds__(256) void fused_rt(
    const float* __restrict__ x, const float* __restrict__ rw,
    int* __restrict__ idx, float* __restrict__ gate,
    const float* __restrict__ w1, ushort_t* __restrict__ w1t,
    const float* __restrict__ w2, ushort_t* __restrict__ w2t)
{
  __shared__ ushort_t tile[64][65];
  int bb = blockIdx.x;
  const int tid = threadIdx.x;
  if (bb < 2048) {
    // ---- router: 4 tokens/block, 1 wave/token (verified r1 body) ----
    constexpr int D = 1024, E = 8;
    int token = (bb * 256 + tid) >> 6;
    int lane = tid & 63;
    const float* xr = x + (size_t)token * D;
    float acc[E];
#pragma unroll
    for (int e = 0; e < E; ++e) acc[e] = 0.f;
    for (int d = lane; d < D; d += 64) {
      float xv = xr[d];
#pragma unroll
      for (int e = 0; e < E; ++e) acc[e] += xv * rw[d * E + e];
    }
#pragma unroll
    for (int off = 32; off >= 1; off >>= 1) {
#pragma unroll
      for (int e = 0; e < E; ++e) acc[e] += __shfl_xor(acc[e], off);
    }
    if (lane == 0) {
      float m = acc[0]; int am = 0;
#pragma unroll
      for (int e = 1; e < E; ++e) { if (acc[e] > m) { m = acc[e]; am = e; } }
      float s = 0.f;
#pragma unroll
      for (int e = 0; e < E; ++e) s += __expf(acc[e] - m);
      idx[token] = am;
      gate[token] = 1.0f / s;   // = max(softmax)
    }
    return;
  }
  bb -= 2048;
  // ---- transpose (r12 body, verified: 0 conflicts, ~104us floor) ----
  const float* in; ushort_t* out; int R, Cc, bx, by, bz;
  if (bb < 8192) {
    in = w1; out = w1t; R = 1024; Cc = 4096;
    bz = bb >> 10; int rr = bb & 1023; bx = rr & 63; by = rr >> 6;   // 64 x 16
  } else {
    bb -= 8192;
    in = w2; out = w2t; R = 4096; Cc = 1024;
    bz = bb >> 10; int rr = bb & 1023; bx = rr & 15; by = rr >> 4;   // 16 x 64
  }
  size_t base = (size_t)bz * (size_t)R * (size_t)Cc;
  int c0 = bx * 64, r0 = by * 64;
  int tx = tid & 63, ty = tid >> 6;
  float v[16];
#pragma unroll
  for (int i = 0; i < 16; ++i)
    v[i] = in[base + (size_t)(r0 + ty + 4 * i) * Cc + c0 + tx];
#pragma unroll
  for (int i = 0; i < 16; ++i)
    tile[ty + 4 * i][tx] = f2h_bits(v[i]);
  __syncthreads();
#pragma unroll
  for (int i = 0; i < 2; ++i) {
    int chunk = tid + i * 256;
    int c = chunk >> 3, g = chunk & 7;
    ushort8v ov;
#pragma unroll
    for (int j = 0; j < 8; ++j) ov[j] = tile[8 * g + j][c];
    *(ushort8v*)(out + base + (size_t)(c0 + c) * R + r0 + 8 * g) = ov;
  }
}

// ---------------- scan: token -> slot (capacity C); slotmap + gate_slot ----------------
__global__ __launch_bounds__(1024) void scan_kernel(
    const int* __restrict__ idx, const float* __restrict__ gate,
    int* __restrict__ slotmap, float* __restrict__ gate_slot)
{
  constexpr int C = 1024, E = 8;
  __shared__ unsigned long long s0[1024];
  __shared__ unsigned long long s1[1024];
  int tid = threadIdx.x;
  int myidx[8];
  unsigned long long c0 = 0, c1 = 0;
#pragma unroll
  for (int j = 0; j < 8; ++j) {
    int e = idx[tid * 8 + j];
    myidx[j] = e;
    if (e < 4) c0 += 1ull << (16 * e);
    else       c1 += 1ull << (16 * (e - 4));
  }
  s0[tid] = c0; s1[tid] = c1;
  __syncthreads();
  for (int off = 1; off < 1024; off <<= 1) {
    unsigned long long b0 = 0, b1 = 0;
    if (tid >= off) { b0 = s0[tid - off]; b1 = s1[tid - off]; }
    __syncthreads();
    s0[tid] += b0; s1[tid] += b1;
    __syncthreads();
  }
  unsigned long long p0 = s0[tid] - c0, p1 = s1[tid] - c1; // exclusive prefix
  unsigned long long t0 = s0[1023], t1 = s1[1023];         // totals
  int cnt[E];
#pragma unroll
  for (int e = 0; e < 4; ++e) {
    cnt[e]     = (int)((p0 >> (16 * e)) & 0xFFFF);
    cnt[4 + e] = (int)((p1 >> (16 * e)) & 0xFFFF);
  }
#pragma unroll
  for (int j = 0; j < 8; ++j) {
    int t = tid * 8 + j;
    int e = myidx[j];
    int pos = cnt[e]++;
    if (pos < C) {
      slotmap[e * C + pos] = t;
      gate_slot[e * C + pos] = gate[t];
    }
  }
  int total[E];
#pragma unroll
  for (int e = 0; e < 4; ++e) {
    total[e]     = (int)((t0 >> (16 * e)) & 0xFFFF);
    total[4 + e] = (int)((t1 >> (16 * e)) & 0xFFFF);
  }
  for (int s = tid; s < E * C; s += 1024) {
    int e = s / C, c = s % C;
    if (c >= total[e]) { slotmap[s] = -1; gate_slot[s] = 0.f; }
  }
}

// ---------------- gather x -> Xe (fp16), zeros for empty slots ----------------
__global__ __launch_bounds__(256) void gather_kernel(
    const float* __restrict__ x, const int* __restrict__ slotmap,
    ushort_t* __restrict__ Xe)
{
  constexpr int D = 1024;
  int slot = blockIdx.x;
  int t = slotmap[slot];
  int tid = threadIdx.x;
  ushort4* dst = (ushort4*)(Xe + (size_t)slot * D);
  ushort4 o;
  if (t >= 0) {
    float4 v = ((const float4*)(x + (size_t)t * D))[tid];
    o.x = f2h_bits(v.x); o.y = f2h_bits(v.y); o.z = f2h_bits(v.z); o.w = f2h_bits(v.w);
  } else {
    o.x = 0; o.y = 0; o.z = 0; o.w = 0;
  }
  dst[tid] = o;
}

// =====================================================================
// 8-phase grouped GEMM, deep-prefetch ledger (r5 schedule, verified 6x).
//   C = A(f16,[M][K]) * Bt(f16,[N][K])^T, 256x256 tiles, BK=64.
// MODE 0: H = relu(C + b1) -> fp16 [E][M][N]
// MODE 1: atomicAdd(out[token], (C + b2/SK)*gate) via slotmap — direct
//         split-K reduction into the fp32 output (memset provides zeros
//         for dropped tokens); replaces the partials+combine round-trip.
// =====================================================================
#define BAR()   asm volatile("s_barrier" ::: "memory")
#define LGKM0() asm volatile("s_waitcnt lgkmcnt(0)" ::: "memory")
#define VM4()   asm volatile("s_waitcnt vmcnt(4)" ::: "memory")
#define VM6()   asm volatile("s_waitcnt vmcnt(6)" ::: "memory")
#define VM0()   asm volatile("s_waitcnt vmcnt(0)" ::: "memory")

#define RD_A0(buf) { _Pragma("unroll") for (int i_ = 0; i_ < 4; ++i_) { \
  _Pragma("unroll") for (int kh_ = 0; kh_ < 2; ++kh_) \
    aS0[i_][kh_] = *(const half8v*)&lds[buf][kh_*KH + (arow + i_*16)*32 + axor]; } }
#define RD_A1(buf) { _Pragma("unroll") for (int i_ = 0; i_ < 4; ++i_) { \
  _Pragma("unroll") for (int kh_ = 0; kh_ < 2; ++kh_) \
    aS1[i_][kh_] = *(const half8v*)&lds[buf][kh_*KH + (arow + (4+i_)*16)*32 + axor]; } }
#define RD_B0(buf) { _Pragma("unroll") for (int j_ = 0; j_ < 2; ++j_) { \
  _Pragma("unroll") for (int kh_ = 0; kh_ < 2; ++kh_) \
    bS0[j_][kh_] = *(const half8v*)&lds[buf][AELEM + kh_*KH + (brow + j_*16)*32 + axor]; } }
#define RD_B1(buf) { _Pragma("unroll") for (int j_ = 0; j_ < 2; ++j_) { \
  _Pragma("unroll") for (int kh_ = 0; kh_ < 2; ++kh_) \
    bS1[j_][kh_] = *(const half8v*)&lds[buf][AELEM + kh_*KH + (brow + (2+j_)*16)*32 + axor]; } }

#define MQ(AS, BS, MB, NB) { __builtin_amdgcn_s_setprio(1); \
  _Pragma("unroll") for (int i_ = 0; i_ < 4; ++i_) { \
  _Pragma("unroll") for (int j_ = 0; j_ < 2; ++j_) { \
    acc[(MB)+i_][(NB)+j_] = __builtin_amdgcn_mfma_f32_16x16x32_f16(AS[i_][0], BS[j_][0], acc[(MB)+i_][(NB)+j_], 0, 0, 0); \
    acc[(MB)+i_][(NB)+j_] = __builtin_amdgcn_mfma_f32_16x16x32_f16(AS[i_][1], BS[j_][1], acc[(MB)+i_][(NB)+j_], 0, 0, 0); } } \
  __builtin_amdgcn_s_setprio(0); }

template<int KFULL, int NTM, int NTN, int SK, int MODE>
__global__ __launch_bounds__(512, 2) void gemm8p(
    const ushort_t* __restrict__ A, const ushort_t* __restrict__ Bt,
    const float* __restrict__ bias,
    ushort_t* __restrict__ Hout, float* __restrict__ outp,
    const int* __restrict__ slotmap, const float* __restrict__ gate_slot)
{
  constexpr int M_ = NTM * 256, N_ = NTN * 256;
  constexpr int KB = KFULL / SK;
  constexpr int NT = KB / 64;
  constexpr int NU = NT / 2;         // >= 2
  constexpr int KH = 256 * 32;       // elems per k-half region
  constexpr int AELEM = 2 * KH;
  constexpr int WPB = NTM * NTN * SK;
  constexpr int NWG = 8 * WPB;
  constexpr int CPX = NWG / 8;

  __shared__ __attribute__((aligned(16))) ushort_t lds[2][2 * AELEM];  // 128 KiB

  const int bid = blockIdx.x;
  const int swz = (bid & 7) * CPX + (bid >> 3);
  const int e   = swz / WPB;
  int r = swz % WPB;
  const int sk  = r / (NTM * NTN);  r %= NTM * NTN;
  const int nt  = r / NTM;
  const int mt  = r % NTM;
  const int kb0 = sk * KB;

  const ushort_t* Ae = A  + (size_t)e * M_ * KFULL + (size_t)(mt * 256) * KFULL + kb0;
  const ushort_t* Be = Bt + (size_t)e * N_ * KFULL + (size_t)(nt * 256) * KFULL + kb0;

  const int tid  = threadIdx.x;
  const int lane = tid & 63;
  const int w    = tid >> 6;
  const int wr   = w >> 2;          // 0..1
  const int wc   = w & 3;           // 0..3
  const int l15  = lane & 15;
  const int axor = ((lane >> 4) ^ ((l15 >> 1) & 3)) << 3;
  const int arow = wr * 128 + l15;
  const int brow = wc * 64 + l15;

  const int srow = tid >> 2;
  const int su   = tid & 3;
  auto stage = [&](int buf, int isB, int h, int ktile) {
    const ushort_t* base = isB ? Be : Ae;
#pragma unroll
    for (int kh = 0; kh < 2; ++kh) {
      int row = h * 128 + srow;
      int ul  = su ^ ((row >> 1) & 3);
      const ushort_t* src = base + (size_t)row * KFULL + ktile * 64 + kh * 32 + ul * 8;
      __builtin_amdgcn_global_load_lds(
          (const __attribute__((address_space(1))) void*)src,
          (__attribute__((address_space(3))) void*)(&lds[buf][isB * AELEM + kh * KH + h * 4096 + tid * 8]),
          16, 0, 0);
    }
  };

  float4v acc[8][4] = {};
  half8v aS0[4][2], aS1[4][2], bS0[2][2], bS1[2][2];

  // prologue: t0 fully into buf0; t1.A0,A1,B0 into buf1 (3 stages in flight)
  stage(0, 0, 0, 0); stage(0, 0, 1, 0); stage(0, 1, 0, 0); stage(0, 1, 1, 0);
  stage(1, 0, 0, 1); stage(1, 0, 1, 1); stage(1, 1, 0, 1);
  VM6(); BAR();
  RD_B0(0); RD_A0(0);          // "ph0" reads: t0 Q00 operands

  for (int u = 0; u < NU - 1; ++u) {
    const int t1 = 2 * u + 1, t2 = 2 * u + 2, t3 = 2 * u + 3;
    // ph1: 12 reads buf0 (rest of t0); stage t1.B1; buf0 reads done -> LGKM0
    RD_B1(0); RD_A1(0); stage(1, 1, 1, t1);
    BAR(); MQ(aS0, bS0, 0, 0); LGKM0(); BAR();
    // ph2: stage t2.A0 into buf0 (free since ph1's LGKM0)
    stage(0, 0, 0, t2);
    BAR(); MQ(aS0, bS1, 0, 2); BAR();
    // ph3: stage t2.A1; VM4 -> t1 fully landed (newest 2 stages = t2.A0/A1 may fly)
    stage(0, 0, 1, t2);
    BAR(); MQ(aS1, bS0, 4, 0); VM4(); BAR();
    // ph4: 12 reads buf1 (t1 Q00 operands); stage t2.B0
    RD_B0(1); RD_A0(1); stage(0, 1, 0, t2);
    BAR(); MQ(aS1, bS1, 4, 2); BAR();
    // ph5: 12 reads buf1 (rest of t1); stage t2.B1; buf1 reads done -> LGKM0
    RD_B1(1); RD_A1(1); stage(0, 1, 1, t2);
    BAR(); MQ(aS0, bS0, 0, 0); LGKM0(); BAR();
    // ph6: stage t3.A0 into buf1
    stage(1, 0, 0, t3);
    BAR(); MQ(aS0, bS1, 0, 2); BAR();
    // ph7: stage t3.A1; VM4 -> t2 fully landed
    stage(1, 0, 1, t3);
    BAR(); MQ(aS1, bS0, 4, 0); VM4(); BAR();
    // ph8: 12 reads buf0 (t2 Q00 operands); stage t3.B0
    RD_B0(0); RD_A0(0); stage(1, 1, 0, t3);
    BAR(); MQ(aS1, bS1, 4, 2); BAR();
  }
  { // final iteration: t0 = NT-2 (buf0), t1 = NT-1 (buf1); only t1.B1 left to stage
    RD_B1(0); RD_A1(0); stage(1, 1, 1, NT - 1);
    BAR(); MQ(aS0, bS0, 0, 0); LGKM0(); BAR();
    BAR(); MQ(aS0, bS1, 0, 2); BAR();
    BAR(); MQ(aS1, bS0, 4, 0); VM0(); BAR();
    RD_B0(1); RD_A0(1);
    BAR(); MQ(aS1, bS1, 4, 2); BAR();
    RD_B1(1); RD_A1(1);
    BAR(); MQ(aS0, bS0, 0, 0); BAR();
    BAR(); MQ(aS0, bS1, 0, 2); BAR();
    BAR(); MQ(aS1, bS0, 4, 0); BAR();
    MQ(aS1, bS1, 4, 2);
  }

  // ---- epilogue: C/D frag mapping col = lane&15, row = (lane>>4)*4 + q ----
  const int lr4   = (lane >> 4) * 4;
  const int mbase = mt * 256 + wr * 128;
  const int nbase = nt * 256 + wc * 64;

  float bv[4];
#pragma unroll
  for (int j = 0; j < 4; ++j) bv[j] = bias[e * N_ + nbase + j * 16 + l15];

  if (MODE == 0) {
    ushort_t* He = Hout + (size_t)e * M_ * N_;
#pragma unroll
    for (int i = 0; i < 8; ++i) {
#pragma unroll
      for (int q = 0; q < 4; ++q) {
        int m = mbase + i * 16 + lr4 + q;
#pragma unroll
        for (int j = 0; j < 4; ++j) {
          float v = acc[i][j][q] + bv[j];
          v = v > 0.f ? v : 0.f;
          He[(size_t)m * N_ + nbase + j * 16 + l15] = f2h_bits(v);
        }
      }
    }
  } else {
    // direct split-K: atomicAdd (C + b2/SK)*gate into out[token]
    const float biasScale = 1.0f / (float)SK;
#pragma unroll
    for (int i = 0; i < 8; ++i) {
#pragma unroll
      for (int q = 0; q < 4; ++q) {
        int slot = e * M_ + mbase + i * 16 + lr4 + q;
        int tkn = slotmap[slot];
        if (tkn < 0) continue;
        float gt = gate_slot[slot];
#pragma unroll
        for (int j = 0; j < 4; ++j) {
          float v = (acc[i][j][q] + bv[j] * biasScale) * gt;
          atomicAdd(&outp[(size_t)tkn * N_ + nbase + j * 16 + l15], v);
        }
      }
    }
  }
}

extern "C" void kernel_launch(void* const* d_in, const int* in_sizes, int n_in,
                              void* d_out, int out_size, void* d_ws, size_t ws_size,
                              hipStream_t stream)
{
  const float* x  = (const float*)d_in[0];
  const float* rw = (const float*)d_in[1];
  const float* w1 = (const float*)d_in[2];
  const float* b1 = (const float*)d_in[3];
  const float* w2 = (const float*)d_in[4];
  const float* b2 = (const float*)d_in[5];
  float* out = (float*)d_out;

  constexpr int D = 1024, E = 8, F = 4096, T = 8192, C = 1024;

  char* p = (char*)d_ws;
  auto take = [&](size_t bytes) { char* r = p; p += (bytes + 255) & ~(size_t)255; return r; };
  ushort_t* w1t = (ushort_t*)take((size_t)E * D * F * 2);  // [E][F][D] f16
  ushort_t* w2t = (ushort_t*)take((size_t)E * F * D * 2);  // [E][D][F] f16
  ushort_t* Xe  = (ushort_t*)take((size_t)E * C * D * 2);  // [E][C][D] f16
  ushort_t* H   = (ushort_t*)take((size_t)E * C * F * 2);  // [E][C][F] f16
  int*      idx = (int*)take((size_t)T * 4);
  float*   gate = (float*)take((size_t)T * 4);
  int*  slotmap = (int*)take((size_t)E * C * 4);
  float* gate_slot = (float*)take((size_t)E * C * 4);

  // fused router (blocks 0..2047) + weight transpose (blocks 2048..18431)
  fused_rt<<<18432, 256, 0, stream>>>(x, rw, idx, gate, w1, w1t, w2, w2t);
  scan_kernel<<<1, 1024, 0, stream>>>(idx, gate, slotmap, gate_slot);
  gather_kernel<<<E * C, 256, 0, stream>>>(x, slotmap, Xe);
  hipMemsetAsync(d_out, 0, (size_t)out_size * sizeof(float), stream);
  // GEMM1: H = relu(Xe * w1 + b1)   M=1024, N=4096, K=1024 -> 512 blocks
  gemm8p<1024, 4, 16, 1, 0><<<512, 512, 0, stream>>>(
      Xe, w1t, b1, H, nullptr, nullptr, nullptr);
  // GEMM2: out += (H*w2 + b2/2)*gate directly (split-K=2, atomicAdd) -> 256 blocks
  gemm8p<4096, 4, 4, 2, 1><<<256, 512, 0, stream>>>(
      H, w2t, b2, nullptr, out, slotmap, gate_slot);
}

// Round 18
// 269.206 us; speedup vs baseline: 1.1249x; 1.1249x over previous
//
#include <hip/hip_runtime.h>
#include <hip/hip_fp16.h>

typedef unsigned short ushort_t;
typedef __attribute__((ext_vector_type(8))) _Float16 half8v;
typedef __attribute__((ext_vector_type(4))) float float4v;
typedef __attribute__((ext_vector_type(8))) unsigned short ushort8v;

#define DEV_INLINE __device__ __forceinline__

DEV_INLINE ushort_t f2h_bits(float f) {
  return __half_as_ushort(__float2half(f));
}

// ---------------- fused: router (blocks 0..2047) + transpose+cvt (r12 body) ----
// Router rides in the transpose launch: the transpose is HBM-bound with
// VALUBusy ~16%, so the router's dot-products absorb into idle issue slots.
// transpose blocks [2048, 10240):  w1 [D][F] -> w1t [F][D]
// transpose blocks [10240, 18432): w2 [F][D] -> w2t [D][F]
__global__ __launch_bounds__(256) void fused_rt(
    const float* __restrict__ x, const float* __restrict__ rw,
    int* __restrict__ idx, float* __restrict__ gate,
    const float* __restrict__ w1, ushort_t* __restrict__ w1t,
    const float* __restrict__ w2, ushort_t* __restrict__ w2t)
{
  __shared__ ushort_t tile[64][65];
  int bb = blockIdx.x;
  const int tid = threadIdx.x;
  if (bb < 2048) {
    // ---- router: 4 tokens/block, 1 wave/token (verified r1 body) ----
    constexpr int D = 1024, E = 8;
    int token = (bb * 256 + tid) >> 6;
    int lane = tid & 63;
    const float* xr = x + (size_t)token * D;
    float acc[E];
#pragma unroll
    for (int e = 0; e < E; ++e) acc[e] = 0.f;
    for (int d = lane; d < D; d += 64) {
      float xv = xr[d];
#pragma unroll
      for (int e = 0; e < E; ++e) acc[e] += xv * rw[d * E + e];
    }
#pragma unroll
    for (int off = 32; off >= 1; off >>= 1) {
#pragma unroll
      for (int e = 0; e < E; ++e) acc[e] += __shfl_xor(acc[e], off);
    }
    if (lane == 0) {
      float m = acc[0]; int am = 0;
#pragma unroll
      for (int e = 1; e < E; ++e) { if (acc[e] > m) { m = acc[e]; am = e; } }
      float s = 0.f;
#pragma unroll
      for (int e = 0; e < E; ++e) s += __expf(acc[e] - m);
      idx[token] = am;
      gate[token] = 1.0f / s;   // = max(softmax)
    }
    return;
  }
  bb -= 2048;
  // ---- transpose (r12 body, verified: 0 conflicts, ~104us floor) ----
  const float* in; ushort_t* out; int R, Cc, bx, by, bz;
  if (bb < 8192) {
    in = w1; out = w1t; R = 1024; Cc = 4096;
    bz = bb >> 10; int rr = bb & 1023; bx = rr & 63; by = rr >> 6;   // 64 x 16
  } else {
    bb -= 8192;
    in = w2; out = w2t; R = 4096; Cc = 1024;
    bz = bb >> 10; int rr = bb & 1023; bx = rr & 15; by = rr >> 4;   // 16 x 64
  }
  size_t base = (size_t)bz * (size_t)R * (size_t)Cc;
  int c0 = bx * 64, r0 = by * 64;
  int tx = tid & 63, ty = tid >> 6;
  float v[16];
#pragma unroll
  for (int i = 0; i < 16; ++i)
    v[i] = in[base + (size_t)(r0 + ty + 4 * i) * Cc + c0 + tx];
#pragma unroll
  for (int i = 0; i < 16; ++i)
    tile[ty + 4 * i][tx] = f2h_bits(v[i]);
  __syncthreads();
#pragma unroll
  for (int i = 0; i < 2; ++i) {
    int chunk = tid + i * 256;
    int c = chunk >> 3, g = chunk & 7;
    ushort8v ov;
#pragma unroll
    for (int j = 0; j < 8; ++j) ov[j] = tile[8 * g + j][c];
    *(ushort8v*)(out + base + (size_t)(c0 + c) * R + r0 + 8 * g) = ov;
  }
}

// ---------------- scan: token -> slot (capacity C), slot <-> token ----------------
__global__ __launch_bounds__(1024) void scan_kernel(
    const int* __restrict__ idx,
    int* __restrict__ slotmap, int* __restrict__ tok2slot)
{
  constexpr int C = 1024, E = 8;
  __shared__ unsigned long long s0[1024];
  __shared__ unsigned long long s1[1024];
  int tid = threadIdx.x;
  int myidx[8];
  unsigned long long c0 = 0, c1 = 0;
#pragma unroll
  for (int j = 0; j < 8; ++j) {
    int e = idx[tid * 8 + j];
    myidx[j] = e;
    if (e < 4) c0 += 1ull << (16 * e);
    else       c1 += 1ull << (16 * (e - 4));
  }
  s0[tid] = c0; s1[tid] = c1;
  __syncthreads();
  for (int off = 1; off < 1024; off <<= 1) {
    unsigned long long b0 = 0, b1 = 0;
    if (tid >= off) { b0 = s0[tid - off]; b1 = s1[tid - off]; }
    __syncthreads();
    s0[tid] += b0; s1[tid] += b1;
    __syncthreads();
  }
  unsigned long long p0 = s0[tid] - c0, p1 = s1[tid] - c1; // exclusive prefix
  unsigned long long t0 = s0[1023], t1 = s1[1023];         // totals
  int cnt[E];
#pragma unroll
  for (int e = 0; e < 4; ++e) {
    cnt[e]     = (int)((p0 >> (16 * e)) & 0xFFFF);
    cnt[4 + e] = (int)((p1 >> (16 * e)) & 0xFFFF);
  }
#pragma unroll
  for (int j = 0; j < 8; ++j) {
    int t = tid * 8 + j;
    int e = myidx[j];
    int pos = cnt[e]++;
    if (pos < C) {
      slotmap[e * C + pos] = t;
      tok2slot[t] = e * C + pos;
    } else {
      tok2slot[t] = -1;
    }
  }
  int total[E];
#pragma unroll
  for (int e = 0; e < 4; ++e) {
    total[e]     = (int)((t0 >> (16 * e)) & 0xFFFF);
    total[4 + e] = (int)((t1 >> (16 * e)) & 0xFFFF);
  }
  for (int s = tid; s < E * C; s += 1024) {
    int e = s / C, c = s % C;
    if (c >= total[e]) slotmap[s] = -1;
  }
}

// ---------------- gather x -> Xe (fp16), zeros for empty slots ----------------
__global__ __launch_bounds__(256) void gather_kernel(
    const float* __restrict__ x, const int* __restrict__ slotmap,
    ushort_t* __restrict__ Xe)
{
  constexpr int D = 1024;
  int slot = blockIdx.x;
  int t = slotmap[slot];
  int tid = threadIdx.x;
  ushort4* dst = (ushort4*)(Xe + (size_t)slot * D);
  ushort4 o;
  if (t >= 0) {
    float4 v = ((const float4*)(x + (size_t)t * D))[tid];
    o.x = f2h_bits(v.x); o.y = f2h_bits(v.y); o.z = f2h_bits(v.z); o.w = f2h_bits(v.w);
  } else {
    o.x = 0; o.y = 0; o.z = 0; o.w = 0;
  }
  dst[tid] = o;
}

// ---------------- combine: out[t] = (p0[slot]+p1[slot]+b2[e]) * gate[t], 0 if dropped ----
__global__ __launch_bounds__(256) void combine_kernel(
    const float* __restrict__ p, const float* __restrict__ b2,
    const int* __restrict__ tok2slot, const float* __restrict__ gate,
    float* __restrict__ out)
{
  constexpr int D = 1024;
  constexpr size_t ECD = (size_t)8 * 1024 * 1024;
  int t = blockIdx.x;
  int d4 = threadIdx.x;
  float4* o = (float4*)(out + (size_t)t * D);
  int slot = tok2slot[t];
  if (slot < 0) { o[d4] = make_float4(0.f, 0.f, 0.f, 0.f); return; }
  int e = slot >> 10;
  float g = gate[t];
  float4 a = ((const float4*)(p + (size_t)slot * D))[d4];
  float4 b = ((const float4*)(p + ECD + (size_t)slot * D))[d4];
  float4 bb = ((const float4*)(b2 + (size_t)e * D))[d4];
  o[d4] = make_float4((a.x + b.x + bb.x) * g, (a.y + b.y + bb.y) * g,
                      (a.z + b.z + bb.z) * g, (a.w + b.w + bb.w) * g);
}

// =====================================================================
// 8-phase grouped GEMM, deep-prefetch ledger (r5 schedule, verified 6x).
//   C = A(f16,[M][K]) * Bt(f16,[N][K])^T, 256x256 tiles, BK=64.
// 512 threads = 8 waves (2M x 4N), per-wave 128x64 output.
// Reads compacted into 12-read phases (ph8+ph1 -> buf0, ph4+ph5 -> buf1);
// stages of the next tile get issue->consume gaps of 6/5/4/3 phases.
// Waits: 2x vmcnt(4) + 2x lgkm0 per iteration.
// MODE 0: H = relu(C + b1) -> fp16 [E][M][N]
// MODE 1: partial[sk][e][m][n] = C (raw fp32; bias+gate in combine)
// =====================================================================
#define BAR()   asm volatile("s_barrier" ::: "memory")
#define LGKM0() asm volatile("s_waitcnt lgkmcnt(0)" ::: "memory")
#define VM4()   asm volatile("s_waitcnt vmcnt(4)" ::: "memory")
#define VM6()   asm volatile("s_waitcnt vmcnt(6)" ::: "memory")
#define VM0()   asm volatile("s_waitcnt vmcnt(0)" ::: "memory")

#define RD_A0(buf) { _Pragma("unroll") for (int i_ = 0; i_ < 4; ++i_) { \
  _Pragma("unroll") for (int kh_ = 0; kh_ < 2; ++kh_) \
    aS0[i_][kh_] = *(const half8v*)&lds[buf][kh_*KH + (arow + i_*16)*32 + axor]; } }
#define RD_A1(buf) { _Pragma("unroll") for (int i_ = 0; i_ < 4; ++i_) { \
  _Pragma("unroll") for (int kh_ = 0; kh_ < 2; ++kh_) \
    aS1[i_][kh_] = *(const half8v*)&lds[buf][kh_*KH + (arow + (4+i_)*16)*32 + axor]; } }
#define RD_B0(buf) { _Pragma("unroll") for (int j_ = 0; j_ < 2; ++j_) { \
  _Pragma("unroll") for (int kh_ = 0; kh_ < 2; ++kh_) \
    bS0[j_][kh_] = *(const half8v*)&lds[buf][AELEM + kh_*KH + (brow + j_*16)*32 + axor]; } }
#define RD_B1(buf) { _Pragma("unroll") for (int j_ = 0; j_ < 2; ++j_) { \
  _Pragma("unroll") for (int kh_ = 0; kh_ < 2; ++kh_) \
    bS1[j_][kh_] = *(const half8v*)&lds[buf][AELEM + kh_*KH + (brow + (2+j_)*16)*32 + axor]; } }

#define MQ(AS, BS, MB, NB) { __builtin_amdgcn_s_setprio(1); \
  _Pragma("unroll") for (int i_ = 0; i_ < 4; ++i_) { \
  _Pragma("unroll") for (int j_ = 0; j_ < 2; ++j_) { \
    acc[(MB)+i_][(NB)+j_] = __builtin_amdgcn_mfma_f32_16x16x32_f16(AS[i_][0], BS[j_][0], acc[(MB)+i_][(NB)+j_], 0, 0, 0); \
    acc[(MB)+i_][(NB)+j_] = __builtin_amdgcn_mfma_f32_16x16x32_f16(AS[i_][1], BS[j_][1], acc[(MB)+i_][(NB)+j_], 0, 0, 0); } } \
  __builtin_amdgcn_s_setprio(0); }

template<int KFULL, int NTM, int NTN, int SK, int MODE>
__global__ __launch_bounds__(512, 2) void gemm8p(
    const ushort_t* __restrict__ A, const ushort_t* __restrict__ Bt,
    const float* __restrict__ bias,
    ushort_t* __restrict__ Hout, float* __restrict__ outp)
{
  constexpr int M_ = NTM * 256, N_ = NTN * 256;
  constexpr int KB = KFULL / SK;
  constexpr int NT = KB / 64;
  constexpr int NU = NT / 2;         // >= 2
  constexpr int KH = 256 * 32;       // elems per k-half region
  constexpr int AELEM = 2 * KH;
  constexpr int WPB = NTM * NTN * SK;
  constexpr int NWG = 8 * WPB;
  constexpr int CPX = NWG / 8;

  __shared__ __attribute__((aligned(16))) ushort_t lds[2][2 * AELEM];  // 128 KiB

  const int bid = blockIdx.x;
  const int swz = (bid & 7) * CPX + (bid >> 3);
  const int e   = swz / WPB;
  int r = swz % WPB;
  const int sk  = r / (NTM * NTN);  r %= NTM * NTN;
  const int nt  = r / NTM;
  const int mt  = r % NTM;
  const int kb0 = sk * KB;

  const ushort_t* Ae = A  + (size_t)e * M_ * KFULL + (size_t)(mt * 256) * KFULL + kb0;
  const ushort_t* Be = Bt + (size_t)e * N_ * KFULL + (size_t)(nt * 256) * KFULL + kb0;

  const int tid  = threadIdx.x;
  const int lane = tid & 63;
  const int w    = tid >> 6;
  const int wr   = w >> 2;          // 0..1
  const int wc   = w & 3;           // 0..3
  const int l15  = lane & 15;
  const int axor = ((lane >> 4) ^ ((l15 >> 1) & 3)) << 3;
  const int arow = wr * 128 + l15;
  const int brow = wc * 64 + l15;

  const int srow = tid >> 2;
  const int su   = tid & 3;
  auto stage = [&](int buf, int isB, int h, int ktile) {
    const ushort_t* base = isB ? Be : Ae;
#pragma unroll
    for (int kh = 0; kh < 2; ++kh) {
      int row = h * 128 + srow;
      int ul  = su ^ ((row >> 1) & 3);
      const ushort_t* src = base + (size_t)row * KFULL + ktile * 64 + kh * 32 + ul * 8;
      __builtin_amdgcn_global_load_lds(
          (const __attribute__((address_space(1))) void*)src,
          (__attribute__((address_space(3))) void*)(&lds[buf][isB * AELEM + kh * KH + h * 4096 + tid * 8]),
          16, 0, 0);
    }
  };

  float4v acc[8][4] = {};
  half8v aS0[4][2], aS1[4][2], bS0[2][2], bS1[2][2];

  // prologue: t0 fully into buf0; t1.A0,A1,B0 into buf1 (3 stages in flight)
  stage(0, 0, 0, 0); stage(0, 0, 1, 0); stage(0, 1, 0, 0); stage(0, 1, 1, 0);
  stage(1, 0, 0, 1); stage(1, 0, 1, 1); stage(1, 1, 0, 1);
  VM6(); BAR();
  RD_B0(0); RD_A0(0);          // "ph0" reads: t0 Q00 operands

  for (int u = 0; u < NU - 1; ++u) {
    const int t1 = 2 * u + 1, t2 = 2 * u + 2, t3 = 2 * u + 3;
    // ph1: 12 reads buf0 (rest of t0); stage t1.B1; buf0 reads done -> LGKM0
    RD_B1(0); RD_A1(0); stage(1, 1, 1, t1);
    BAR(); MQ(aS0, bS0, 0, 0); LGKM0(); BAR();
    // ph2: stage t2.A0 into buf0 (free since ph1's LGKM0)
    stage(0, 0, 0, t2);
    BAR(); MQ(aS0, bS1, 0, 2); BAR();
    // ph3: stage t2.A1; VM4 -> t1 fully landed (newest 2 stages = t2.A0/A1 may fly)
    stage(0, 0, 1, t2);
    BAR(); MQ(aS1, bS0, 4, 0); VM4(); BAR();
    // ph4: 12 reads buf1 (t1 Q00 operands); stage t2.B0
    RD_B0(1); RD_A0(1); stage(0, 1, 0, t2);
    BAR(); MQ(aS1, bS1, 4, 2); BAR();
    // ph5: 12 reads buf1 (rest of t1); stage t2.B1; buf1 reads done -> LGKM0
    RD_B1(1); RD_A1(1); stage(0, 1, 1, t2);
    BAR(); MQ(aS0, bS0, 0, 0); LGKM0(); BAR();
    // ph6: stage t3.A0 into buf1
    stage(1, 0, 0, t3);
    BAR(); MQ(aS0, bS1, 0, 2); BAR();
    // ph7: stage t3.A1; VM4 -> t2 fully landed
    stage(1, 0, 1, t3);
    BAR(); MQ(aS1, bS0, 4, 0); VM4(); BAR();
    // ph8: 12 reads buf0 (t2 Q00 operands); stage t3.B0
    RD_B0(0); RD_A0(0); stage(1, 1, 0, t3);
    BAR(); MQ(aS1, bS1, 4, 2); BAR();
  }
  { // final iteration: t0 = NT-2 (buf0), t1 = NT-1 (buf1); only t1.B1 left to stage
    RD_B1(0); RD_A1(0); stage(1, 1, 1, NT - 1);
    BAR(); MQ(aS0, bS0, 0, 0); LGKM0(); BAR();
    BAR(); MQ(aS0, bS1, 0, 2); BAR();
    BAR(); MQ(aS1, bS0, 4, 0); VM0(); BAR();
    RD_B0(1); RD_A0(1);
    BAR(); MQ(aS1, bS1, 4, 2); BAR();
    RD_B1(1); RD_A1(1);
    BAR(); MQ(aS0, bS0, 0, 0); BAR();
    BAR(); MQ(aS0, bS1, 0, 2); BAR();
    BAR(); MQ(aS1, bS0, 4, 0); BAR();
    MQ(aS1, bS1, 4, 2);
  }

  // ---- epilogue: C/D frag mapping col = lane&15, row = (lane>>4)*4 + q ----
  const int lr4   = (lane >> 4) * 4;
  const int mbase = mt * 256 + wr * 128;
  const int nbase = nt * 256 + wc * 64;

  if (MODE == 0) {
    float bv[4];
#pragma unroll
    for (int j = 0; j < 4; ++j) bv[j] = bias[e * N_ + nbase + j * 16 + l15];
    ushort_t* He = Hout + (size_t)e * M_ * N_;
#pragma unroll
    for (int i = 0; i < 8; ++i) {
#pragma unroll
      for (int q = 0; q < 4; ++q) {
        int m = mbase + i * 16 + lr4 + q;
#pragma unroll
        for (int j = 0; j < 4; ++j) {
          float v = acc[i][j][q] + bv[j];
          v = v > 0.f ? v : 0.f;
          He[(size_t)m * N_ + nbase + j * 16 + l15] = f2h_bits(v);
        }
      }
    }
  } else {
    float* pe = outp + ((size_t)(sk * 8 + e)) * (size_t)M_ * N_;
#pragma unroll
    for (int i = 0; i < 8; ++i) {
#pragma unroll
      for (int q = 0; q < 4; ++q) {
        int m = mbase + i * 16 + lr4 + q;
#pragma unroll
        for (int j = 0; j < 4; ++j) {
          pe[(size_t)m * N_ + nbase + j * 16 + l15] = acc[i][j][q];
        }
      }
    }
  }
}

extern "C" void kernel_launch(void* const* d_in, const int* in_sizes, int n_in,
                              void* d_out, int out_size, void* d_ws, size_t ws_size,
                              hipStream_t stream)
{
  const float* x  = (const float*)d_in[0];
  const float* rw = (const float*)d_in[1];
  const float* w1 = (const float*)d_in[2];
  const float* b1 = (const float*)d_in[3];
  const float* w2 = (const float*)d_in[4];
  const float* b2 = (const float*)d_in[5];
  float* out = (float*)d_out;

  constexpr int D = 1024, E = 8, F = 4096, T = 8192, C = 1024;

  char* p = (char*)d_ws;
  auto take = [&](size_t bytes) { char* r = p; p += (bytes + 255) & ~(size_t)255; return r; };
  ushort_t* w1t = (ushort_t*)take((size_t)E * D * F * 2);  // [E][F][D] f16; reused as partials
  ushort_t* w2t = (ushort_t*)take((size_t)E * F * D * 2);  // [E][D][F] f16
  ushort_t* Xe  = (ushort_t*)take((size_t)E * C * D * 2);  // [E][C][D] f16
  ushort_t* H   = (ushort_t*)take((size_t)E * C * F * 2);  // [E][C][F] f16
  int*      idx = (int*)take((size_t)T * 4);
  float*   gate = (float*)take((size_t)T * 4);
  int*  slotmap = (int*)take((size_t)E * C * 4);
  int* tok2slot = (int*)take((size_t)T * 4);

  float* partials = (float*)w1t;   // 2 x [E][C][D] fp32 = 64 MB, aliases dead w1t

  // fused router (blocks 0..2047) + weight transpose (blocks 2048..18431)
  fused_rt<<<18432, 256, 0, stream>>>(x, rw, idx, gate, w1, w1t, w2, w2t);
  scan_kernel<<<1, 1024, 0, stream>>>(idx, slotmap, tok2slot);
  gather_kernel<<<E * C, 256, 0, stream>>>(x, slotmap, Xe);
  // GEMM1: H = relu(Xe * w1 + b1)   M=1024, N=4096, K=1024 -> 512 blocks
  gemm8p<1024, 4, 16, 1, 0><<<512, 512, 0, stream>>>(Xe, w1t, b1, H, nullptr);
  // GEMM2: partials[sk] = H * w2 (split-K=2, 256^2 tiles) -> 256 blocks
  gemm8p<4096, 4, 4, 2, 1><<<256, 512, 0, stream>>>(H, w2t, nullptr, nullptr, partials);
  // combine: out[t] = (p0+p1+b2)*gate, zeros for dropped tokens
  combine_kernel<<<T, 256, 0, stream>>>(partials, b2, tok2slot, gate, out);
}